// Round 1
// baseline (31092.038 us; speedup 1.0000x reference)
//
#include <hip/hip_runtime.h>
#include <hip/hip_bf16.h>
#include <math.h>

// Problem constants
#define B  64
#define T  1024
#define I  512
#define O  512
#define NZ 2048      // 4*O
#define K  1024      // I + O
#define EPS 1e-5f

// ---------------------------------------------------------------------------
// K0: initialize h, c from init_hx / init_cx (broadcast over batch)
// ---------------------------------------------------------------------------
__global__ __launch_bounds__(256) void init_state(
    const float* __restrict__ init_hx, const float* __restrict__ init_cx,
    float* __restrict__ h, float* __restrict__ c) {
  int idx = blockIdx.x * 256 + threadIdx.x;   // 0 .. B*O-1
  if (idx < B * O) {
    int o = idx & (O - 1);
    h[idx] = init_hx[o];
    c[idx] = init_cx[o];
  }
}

// ---------------------------------------------------------------------------
// K1: z[b][n] = sum_k cat(x_t, h)[b][k] * W[n][k]   for one timestep t
// grid: 256 blocks, each owns 8 consecutive n rows, all 64 b.
// K is processed in 4 chunks of 256; cat chunk staged in LDS (coalesced),
// W rows read directly from global with wave-uniform addresses (L1 broadcast).
// wave w handles n = n0+2w, n0+2w+1 ; lane = b.
// ---------------------------------------------------------------------------
#define KC 256
#define PAD 4
#define LDS_STRIDE (KC + PAD)   // 260 floats; 260*4=1040 bytes = 65*16 (16B aligned rows)

__global__ __launch_bounds__(256) void zstep(
    const float* __restrict__ x, const float* __restrict__ W,
    const float* __restrict__ h, float* __restrict__ z, int t) {
  __shared__ float cat[B * LDS_STRIDE];

  const int tid  = threadIdx.x;
  const int wv   = tid >> 6;     // wave 0..3
  const int lane = tid & 63;     // = batch row b for compute phase
  const int n0   = blockIdx.x * 8;
  const int j0   = 2 * wv;
  const int j1   = 2 * wv + 1;

  const float* __restrict__ wrow0 = W + (size_t)(n0 + j0) * K;
  const float* __restrict__ wrow1 = W + (size_t)(n0 + j1) * K;

  float acc0 = 0.f, acc1 = 0.f;

  for (int ch = 0; ch < 4; ++ch) {
    const int base_k = ch * KC;
    // ---- stage cat chunk: 64 rows x 256 floats = 4096 float4, 16 per thread
    #pragma unroll
    for (int i = 0; i < 16; ++i) {
      int idx = tid + i * 256;        // 0..4095
      int b   = idx >> 6;             // 64 float4 per row
      int k4  = idx & 63;
      float4 v;
      if (ch < 2) {
        const float* src = x + ((size_t)(b * T + t)) * I + base_k + k4 * 4;
        v = *(const float4*)src;
      } else {
        const float* src = h + b * O + (base_k - I) + k4 * 4;
        v = *(const float4*)src;
      }
      *(float4*)&cat[b * LDS_STRIDE + k4 * 4] = v;
    }
    __syncthreads();

    // ---- compute: each wave: 2 n-rows, lane = b
    const float* __restrict__ cr  = &cat[lane * LDS_STRIDE];
    const float* __restrict__ wr0 = wrow0 + base_k;
    const float* __restrict__ wr1 = wrow1 + base_k;
    #pragma unroll 8
    for (int k4 = 0; k4 < 64; ++k4) {
      float4 cv = *(const float4*)&cr[k4 * 4];
      float4 a  = *(const float4*)&wr0[k4 * 4];
      float4 bb = *(const float4*)&wr1[k4 * 4];
      acc0 += cv.x * a.x  + cv.y * a.y  + cv.z * a.z  + cv.w * a.w;
      acc1 += cv.x * bb.x + cv.y * bb.y + cv.z * bb.z + cv.w * bb.w;
    }
    __syncthreads();
  }

  z[lane * NZ + n0 + j0] = acc0;
  z[lane * NZ + n0 + j1] = acc1;
}

// ---------------------------------------------------------------------------
// K2: per-batch layernorm over 2048, gates, c/h update, write out[b][t][:]
// grid: 64 blocks (one per b) x 256 threads
// ---------------------------------------------------------------------------
__global__ __launch_bounds__(256) void gatestep(
    const float* __restrict__ z, const float* __restrict__ gamma,
    const float* __restrict__ beta, float* __restrict__ h,
    float* __restrict__ c, float* __restrict__ out, int t) {
  const int b   = blockIdx.x;
  const int tid = threadIdx.x;
  const float* __restrict__ zb = z + b * NZ;

  __shared__ float red1[4], red2[4];

  // ---- stats: sum, sumsq over 2048
  float s1 = 0.f, s2 = 0.f;
  #pragma unroll
  for (int i = tid; i < NZ; i += 256) {
    float v = zb[i];
    s1 += v;
    s2 += v * v;
  }
  #pragma unroll
  for (int off = 32; off > 0; off >>= 1) {
    s1 += __shfl_down(s1, off, 64);
    s2 += __shfl_down(s2, off, 64);
  }
  if ((tid & 63) == 0) {
    red1[tid >> 6] = s1;
    red2[tid >> 6] = s2;
  }
  __syncthreads();
  float S1 = red1[0] + red1[1] + red1[2] + red1[3];
  float S2 = red2[0] + red2[1] + red2[2] + red2[3];
  float mean = S1 * (1.f / NZ);
  float var  = S2 * (1.f / NZ) - mean * mean;
  float rstd = rsqrtf(var + EPS);

  // ---- gates: 512 o across 256 threads (2 each)
  for (int o = tid; o < O; o += 256) {
    float zf = (zb[o         ] - mean) * rstd * gamma[o         ] + beta[o         ];
    float zi = (zb[O   + o   ] - mean) * rstd * gamma[O   + o   ] + beta[O   + o   ];
    float zo = (zb[2*O + o   ] - mean) * rstd * gamma[2*O + o   ] + beta[2*O + o   ];
    float zg = (zb[3*O + o   ] - mean) * rstd * gamma[3*O + o   ] + beta[3*O + o   ];

    float fg = 1.f / (1.f + expf(-zf));
    float ig = 1.f / (1.f + expf(-zi));
    float og = 1.f / (1.f + expf(-zo));
    float gg = 0.5f * zg * (1.f + erff(zg * 0.70710678118654752f));

    int   ci = b * O + o;
    float cn = fg * c[ci] + ig * gg;
    float hn = og * cn;
    c[ci] = cn;
    h[ci] = hn;
    out[((size_t)b * T + t) * O + o] = hn;
  }
}

// ---------------------------------------------------------------------------
extern "C" void kernel_launch(void* const* d_in, const int* in_sizes, int n_in,
                              void* d_out, int out_size, void* d_ws, size_t ws_size,
                              hipStream_t stream) {
  const float* x       = (const float*)d_in[0];
  const float* W       = (const float*)d_in[1];
  const float* gamma   = (const float*)d_in[2];
  const float* beta    = (const float*)d_in[3];
  const float* init_hx = (const float*)d_in[4];
  const float* init_cx = (const float*)d_in[5];
  float* out = (float*)d_out;

  float* h = (float*)d_ws;          // B*O
  float* c = h + B * O;             // B*O
  float* z = c + B * O;             // B*NZ
  (void)ws_size; (void)in_sizes; (void)n_in; (void)out_size;

  init_state<<<(B * O + 255) / 256, 256, 0, stream>>>(init_hx, init_cx, h, c);

  for (int t = 0; t < T; ++t) {
    zstep<<<NZ / 8, 256, 0, stream>>>(x, W, h, z, t);
    gatestep<<<B, 256, 0, stream>>>(z, gamma, beta, h, c, out, t);
  }
}